// Round 5
// baseline (1275.364 us; speedup 1.0000x reference)
//
#include <hip/hip_runtime.h>
#include <hip/hip_bf16.h>

typedef __attribute__((ext_vector_type(8))) short short8;
typedef __attribute__((ext_vector_type(4))) float f32x4;
typedef unsigned short u16;

// Problem constants
#define BB 512     // batch
#define HH 1024    // hidden
#define TT 25      // decoder steps
#define CTB 128    // ct slices (each owns 8 hidden cols -> 48 Wc rows)

__device__ __forceinline__ float sigm(float x){ return 1.f/(1.f+__expf(-x)); }
__device__ __forceinline__ float tanh_(float x){
  float e = __expf(-2.f*fabsf(x));
  float t = (1.f-e)/(1.f+e);
  return copysignf(t, x);
}
__device__ __forceinline__ u16 f2bf(float x){
  union { float f; unsigned u; } v; v.f = x;
  unsigned r = v.u + 0x7FFFu + ((v.u>>16)&1u);
  return (u16)(r>>16);
}

#if __has_builtin(__builtin_amdgcn_global_load_lds)
#define GLOAD_LDS16(g, l) __builtin_amdgcn_global_load_lds( \
    (const __attribute__((address_space(1))) void*)(g), \
    (__attribute__((address_space(3))) void*)(l), 16, 0, 0)
#define HAVE_GLL 1
#else
#define HAVE_GLL 0
#endif

// Wcp layout: per ct slice (8 hidden cols), 48 rows (r = gate*8 + u, gates:
// 0=gir 1=giz 2=gin 3=ghr 4=ghz 5=ghn), pre-packed in MFMA B-frag order:
// elem idx = ct*49152 + ((kit*3 + nf)*64 + lane)*8 + e
__device__ __forceinline__ size_t wc_idx(int ct, int r, int k){
  int nf = r>>4, rl = r&15, kit = k>>5, k31 = k&31;
  int lane = rl | (((k31>>3)&3)<<4);
  return (size_t)ct*49152 + ((size_t)(kit*3+nf)*64 + (size_t)lane)*8 + (k31&7);
}

// ---- prep 1: Whh -> Wcp gate rows 3..5 (+cbias), Wout -> WoT (bf16 [96][1024])
__global__ void k_prep_cast(const float* __restrict__ Whh, const float* __restrict__ bhh,
                            const float* __restrict__ Wout,
                            u16* __restrict__ Wcp, float* __restrict__ cbias,
                            u16* __restrict__ WoT){
  int bid = blockIdx.x, tid = threadIdx.x;
  if (bid < 3072){
    int g1 = bid >> 10, j = bid & 1023;
    int ct = j >> 3, u = j & 7, r = (3+g1)*8 + u;
    const float* src = Whh + (size_t)bid*1024;
    if (tid < 128){
      int k0 = tid*8;
      size_t base = wc_idx(ct, r, k0);
      #pragma unroll
      for (int i=0;i<8;i++) Wcp[base+i] = f2bf(src[k0+i]);
    }
    if (!tid) cbias[ct*48 + r] = bhh[bid];
  } else {
    int d = bid - 3072;
    for (int k = tid; k < 1024; k += 256)
      WoT[(size_t)d*1024 + k] = f2bf(Wout[(size_t)k*96 + d]);
  }
}

// ---- prep 2: Wx[n][k] = sum_d Wih[n][d]*Wout[k][d]  (out-proj folded into gi path)
__global__ void k_prep_wx(const float* __restrict__ Wih, const float* __restrict__ Wout,
                          u16* __restrict__ Wcp){
  __shared__ float sWih[32][97];
  __shared__ float sWo[64][97];
  int tid = threadIdx.x;
  int nt = blockIdx.x % 96, kt = blockIdx.x / 96;   // n-tile 32, k-tile 64
  for (int i = tid; i < 32*96; i += 256){ int r2=i/96, d=i%96; sWih[r2][d] = Wih[(size_t)(nt*32+r2)*96 + d]; }
  for (int i = tid; i < 64*96; i += 256){ int r2=i/96, d=i%96; sWo[r2][d]  = Wout[(size_t)(kt*64+r2)*96 + d]; }
  __syncthreads();
  int ni = tid & 31, kb = tid >> 5;    // thread owns 8 consecutive k
  float acc[8];
  #pragma unroll
  for (int i=0;i<8;i++) acc[i]=0.f;
  for (int d = 0; d < 96; d++){
    float a = sWih[ni][d];
    #pragma unroll
    for (int i=0;i<8;i++) acc[i] += a * sWo[kb*8 + i][d];
  }
  int n = nt*32 + ni;
  int g = n >> 10, j = n & 1023;
  int ct = j >> 3, u = j & 7, r = g*8 + u;
  size_t base = wc_idx(ct, r, kt*64 + kb*8);
  #pragma unroll
  for (int i=0;i<8;i++) Wcp[base+i] = f2bf(acc[i]);
}

// ---- prep 3: cbias gi rows: bih[n] + sum_d bout[d]*Wih[n][d]
__global__ void k_prep_cx(const float* __restrict__ Wih, const float* __restrict__ bih,
                          const float* __restrict__ bout, float* __restrict__ cbias){
  int n = blockIdx.x*256 + threadIdx.x;
  if (n >= 3072) return;
  float acc = bih[n];
  const float* wrow = Wih + (size_t)n*96;
  for (int d = 0; d < 96; d++) acc += bout[d]*wrow[d];
  int g = n >> 10, j = n & 1023;
  cbias[(j>>3)*48 + g*8 + (j&7)] = acc;
}

// ---- step 0: h1 = gru(p, 0) in fp32 (gh = bhh exactly since h=0)
// h_f32 COL-MAJOR [1024][512]; h_bf row-major [512][1024]. Also resets barrier cnt.
__global__ void k_step0(const float* __restrict__ dec_in, const float* __restrict__ Wih,
                        const float* __restrict__ bih, const float* __restrict__ bhh,
                        float* __restrict__ h_f32, u16* __restrict__ h_bf,
                        unsigned* __restrict__ cnt){
  if (blockIdx.x == 0 && threadIdx.x == 0) cnt[0] = 0u;
  __shared__ float sP[64][97];
  __shared__ float sW[64][97];
  int tid = threadIdx.x;
  int bt = blockIdx.x & 7;
  int jt = blockIdx.x >> 3;
  for (int i = tid; i < 64*96; i += 256){ int r=i/96, d=i%96; sP[r][d] = dec_in[(size_t)(bt*64+r)*96 + d]; }
  int tb = tid >> 4, tj = tid & 15;
  float gg[3][4][4];
  for (int g = 0; g < 3; g++){
    __syncthreads();
    for (int i = tid; i < 64*96; i += 256){ int r=i/96, d=i%96; sW[r][d] = Wih[((size_t)g*1024 + jt*64 + r)*96 + d]; }
    __syncthreads();
    float acc[4][4];
    #pragma unroll
    for (int x=0;x<4;x++)
      #pragma unroll
      for (int y=0;y<4;y++) acc[x][y]=0.f;
    for (int d = 0; d < 96; d++){
      float a[4], wv[4];
      #pragma unroll
      for (int x=0;x<4;x++) a[x]  = sP[tb + x*16][d];
      #pragma unroll
      for (int y=0;y<4;y++) wv[y] = sW[tj + y*16][d];
      #pragma unroll
      for (int x=0;x<4;x++)
        #pragma unroll
        for (int y=0;y<4;y++) acc[x][y] += a[x]*wv[y];
    }
    #pragma unroll
    for (int x=0;x<4;x++)
      #pragma unroll
      for (int y=0;y<4;y++) gg[g][x][y] = acc[x][y];
  }
  #pragma unroll
  for (int x=0;x<4;x++)
    #pragma unroll
    for (int y=0;y<4;y++){
      int b = bt*64 + tb + x*16;
      int j = jt*64 + tj + y*16;
      float gir = gg[0][x][y] + bih[j];
      float giz = gg[1][x][y] + bih[1024+j];
      float gin = gg[2][x][y] + bih[2048+j];
      float r = sigm(gir + bhh[j]);
      float z = sigm(giz + bhh[1024+j]);
      float nn = tanh_(gin + r*bhh[2048+j]);
      float h = (1.f - z)*nn;
      h_f32[(size_t)j*512 + b] = h;
      h_bf [(size_t)b*1024 + j] = f2bf(h);
    }
}

// ---- fused out-projection tile: pred[outIdx] rows [bt*256+bm*16,+16) cols [bn*16,+16)
__device__ __forceinline__ void pred_tile(const u16* __restrict__ hin_bf,
    const u16* __restrict__ WoT, const float* __restrict__ bout,
    float* __restrict__ pred, int bt, int ct, int l16, int lk, int outIdx){
  int bm = ct/6, bn = ct%6;
  const short8* Aq = (const short8*)hin_bf + (size_t)(bt*256 + bm*16 + l16)*128 + lk;
  const short8* Bq = (const short8*)WoT   + (size_t)(bn*16 + l16)*128 + lk;
  short8 qa[4], qb[4];
  #pragma unroll
  for (int d=0; d<4; d++){ qa[d]=Aq[d*4]; qb[d]=Bq[d*4]; }
  f32x4 accp = {0.f,0.f,0.f,0.f};
  #pragma unroll
  for (int kit=0; kit<32; kit++){
    int slot = kit & 3;
    short8 a = qa[slot], b = qb[slot];
    if (kit < 28){ qa[slot]=Aq[(kit+4)*4]; qb[slot]=Bq[(kit+4)*4]; }
    accp = __builtin_amdgcn_mfma_f32_16x16x32_bf16(a, b, accp, 0,0,0);
  }
  int c = bn*16 + l16;
  float bb = bout[c];
  #pragma unroll
  for (int j=0;j<4;j++){
    int row = bt*256 + bm*16 + lk*4 + j;
    pred[(size_t)row*2400 + (size_t)outIdx*96 + c] = accp[j] + bb;
  }
}

// ---- persistent kernel: all steps in one launch; Wc slice lives in LDS.
// 256 blocks x 512 threads (1 block/CU). Custom agent-scope barrier:
// thread 0 per block does fence + atomic add + spin; pred work hides in slack.
// Triple-buffered h so pred (reading h_t after release) can't race step t+1 writes.
__global__ __launch_bounds__(512)
void k_persist2(u16* __restrict__ hb0, float* __restrict__ hf0,
                u16* __restrict__ hb1, float* __restrict__ hf1,
                u16* __restrict__ hb2, float* __restrict__ hf2,
                const u16* __restrict__ Wcp, const float* __restrict__ cbias,
                const u16* __restrict__ WoT, const float* __restrict__ bout,
                float* __restrict__ pred, unsigned* __restrict__ cnt){
  __shared__ short8 sB[6144];       // 96 KB: Wc slice, staged ONCE
  int b = blockIdx.x, tid = threadIdx.x;
  int lane = tid & 63, w = tid >> 6;          // 8 waves
  int l16 = lane & 15, lk = lane >> 4;
  int r8 = b & 7;
  int bt = r8 >> 2;                           // batch half
  int ct = (b >> 3)*4 + (r8 & 3);             // slice [0,128)

  const short8* Wblk = (const short8*)Wcp + (size_t)ct*6144;
#if HAVE_GLL
  #pragma unroll
  for (int it = 0; it < 12; it++){
    int i = it*512 + tid;
    GLOAD_LDS16(Wblk + i, &sB[i]);
  }
#else
  for (int i = tid; i < 6144; i += 512) sB[i] = Wblk[i];
#endif

  float c0 = cbias[ct*48 +  0 + l16];
  float c1 = cbias[ct*48 + 16 + l16];
  float c2 = cbias[ct*48 + 32 + l16];
  bool hiB = (l16 & 8) != 0;
  int colg = ct*8 + (l16 & 7);
  int rowA = bt*256 + w*32;                   // wave owns 32 batch rows
  bool doPred = (ct < 96) && (w == 7);

  u16 *pin_b = hb0, *pout_b = hb1, *pspare_b = hb2;
  float *pin_f = hf0, *pout_f = hf1, *pspare_f = hf2;

  __syncthreads();   // staging complete

  for (int t = 1; t <= 24; ++t){
    // ---- A-prefetch ring (depth 8) + hold prefetch
    const short8* Ap = (const short8*)pin_b + (size_t)(rowA + l16)*128 + lk;
    short8 r0_[8], r1_[8];
    #pragma unroll
    for (int d = 0; d < 8; d++){ r0_[d] = Ap[d*4]; r1_[d] = Ap[d*4 + 2048]; }
    float hold[2][4];
    if (!hiB){
      #pragma unroll
      for (int mf = 0; mf < 2; mf++){
        f32x4 h4 = *(const f32x4*)(pin_f + (size_t)colg*512 + rowA + mf*16 + lk*4);
        hold[mf][0]=h4[0]; hold[mf][1]=h4[1]; hold[mf][2]=h4[2]; hold[mf][3]=h4[3];
      }
    }

    // ---- recurrence: C = h_t[half] @ WcSlice^T
    f32x4 acc[2][3];
    #pragma unroll
    for (int m=0;m<2;m++)
      #pragma unroll
      for (int nf=0;nf<3;nf++) acc[m][nf] = f32x4{0.f,0.f,0.f,0.f};
    #pragma unroll
    for (int kit = 0; kit < 32; kit++){
      const int slot = kit & 7;
      short8 a0 = r0_[slot], a1 = r1_[slot];
      if (kit < 24){ r0_[slot] = Ap[(kit+8)*4]; r1_[slot] = Ap[(kit+8)*4 + 2048]; }
      const short8* Bs = &sB[kit*192 + lane];
      short8 b0 = Bs[0], b1 = Bs[64], b2 = Bs[128];
      acc[0][0] = __builtin_amdgcn_mfma_f32_16x16x32_bf16(a0, b0, acc[0][0], 0,0,0);
      acc[1][0] = __builtin_amdgcn_mfma_f32_16x16x32_bf16(a1, b0, acc[1][0], 0,0,0);
      acc[0][1] = __builtin_amdgcn_mfma_f32_16x16x32_bf16(a0, b1, acc[0][1], 0,0,0);
      acc[1][1] = __builtin_amdgcn_mfma_f32_16x16x32_bf16(a1, b1, acc[1][1], 0,0,0);
      acc[0][2] = __builtin_amdgcn_mfma_f32_16x16x32_bf16(a0, b2, acc[0][2], 0,0,0);
      acc[1][2] = __builtin_amdgcn_mfma_f32_16x16x32_bf16(a1, b2, acc[1][2], 0,0,0);
    }

    // ---- gates via lane pair (l, l^8); lo: gir,gin,ghz  hi: giz,ghr,ghn
    #pragma unroll
    for (int mf=0; mf<2; mf++){
      #pragma unroll
      for (int j=0;j<4;j++){
        int batch = rowA + mf*16 + lk*4 + j;
        float g0 = acc[mf][0][j] + c0;
        float g1 = acc[mf][1][j] + c1;
        float g2 = acc[mf][2][j] + c2;
        float v1 = hiB ? g1 : g2;
        float w1 = __shfl_xor(v1, 8, 64);
        float rz = sigm(g0 + w1);
        float w2 = __shfl_xor(rz, 8, 64);
        float v3 = hiB ? (w2 * g2) : 0.f;
        float w3 = __shfl_xor(v3, 8, 64);
        if (!hiB){
          float nn = tanh_(g1 + w3);
          float z  = w2;
          float hnew = (1.f - z)*nn + z*hold[mf][j];
          pout_f[(size_t)colg*512 + batch] = hnew;
          pout_b[(size_t)batch*1024 + colg] = f2bf(hnew);
        }
      }
    }

    // ---- barrier: release (thread 0 only), pred in the slack, acquire
    __syncthreads();                       // all stores of this block drained
    if (tid == 0){
      __threadfence();                     // L2 writeback: block's h visible at L3
      __hip_atomic_fetch_add(cnt, 1u, __ATOMIC_RELEASE, __HIP_MEMORY_SCOPE_AGENT);
    }
    if (doPred) pred_tile(pin_b, WoT, bout, pred, bt, ct, l16, lk, t-1);
    if (tid == 0){
      unsigned target = 256u * (unsigned)t;
      while (__hip_atomic_load(cnt, __ATOMIC_RELAXED, __HIP_MEMORY_SCOPE_AGENT) < target)
        __builtin_amdgcn_s_sleep(2);
      __threadfence();                     // L2 invalidate: see others' h
    }
    __syncthreads();

    // rotate buffers: in <- out <- spare <- in
    u16* tb_ = pin_b;  pin_b = pout_b;  pout_b = pspare_b;  pspare_b = tb_;
    float* tf_ = pin_f; pin_f = pout_f; pout_f = pspare_f; pspare_f = tf_;
  }
  // final pred index 24 from h_25 (written at t=24 into buffer 24%3==0 -> hb0)
  if (doPred) pred_tile(hb0, WoT, bout, pred, bt, ct, l16, lk, 24);
}

extern "C" void kernel_launch(void* const* d_in, const int* in_sizes, int n_in,
                              void* d_out, int out_size, void* d_ws, size_t ws_size,
                              hipStream_t stream){
  // inputs: 0 enc_in, 1 dec_in, 2..5 enc_* (DEAD CODE), 6 dec_Wih, 7 dec_Whh,
  //         8 dec_bih, 9 dec_bhh, 10 W_out, 11 b_out
  const float* dec_in = (const float*)d_in[1];
  const float* Wih  = (const float*)d_in[6];
  const float* Whh  = (const float*)d_in[7];
  const float* bih  = (const float*)d_in[8];
  const float* bhh  = (const float*)d_in[9];
  const float* Wout = (const float*)d_in[10];
  const float* bout = (const float*)d_in[11];
  float* pred = (float*)d_out;   // [512][25][96] fp32

  char* ws = (char*)d_ws;
  size_t off = 0;
  u16* Wcp = (u16*)(ws + off);   off += (size_t)CTB*48*1024*2;     // 12.58 MB
  u16* WoT = (u16*)(ws + off);   off += (size_t)96*1024*2;
  float* cbias = (float*)(ws + off); off += (size_t)6144*4;
  off = (off + 255) & ~(size_t)255;
  float* hf0 = (float*)(ws + off); off += (size_t)BB*HH*4;   // col-major [1024][512]
  float* hf1 = (float*)(ws + off); off += (size_t)BB*HH*4;
  float* hf2 = (float*)(ws + off); off += (size_t)BB*HH*4;
  u16* hb0 = (u16*)(ws + off);     off += (size_t)BB*HH*2;   // row-major [512][1024]
  u16* hb1 = (u16*)(ws + off);     off += (size_t)BB*HH*2;
  u16* hb2 = (u16*)(ws + off);     off += (size_t)BB*HH*2;
  off = (off + 255) & ~(size_t)255;
  unsigned* cnt = (unsigned*)(ws + off); off += 256;

  k_prep_cast<<<3168, 256, 0, stream>>>(Whh, bhh, Wout, Wcp, cbias, WoT);
  k_prep_wx  <<<1536, 256, 0, stream>>>(Wih, Wout, Wcp);
  k_prep_cx  <<<12,   256, 0, stream>>>(Wih, bih, bout, cbias);
  k_step0    <<<128,  256, 0, stream>>>(dec_in, Wih, bih, bhh, hf0, hb0, cnt);

  void* kargs[] = {(void*)&hb0, (void*)&hf0, (void*)&hb1, (void*)&hf1,
                   (void*)&hb2, (void*)&hf2, (void*)&Wcp, (void*)&cbias,
                   (void*)&WoT, (void*)&bout, (void*)&pred, (void*)&cnt};
  hipLaunchCooperativeKernel((const void*)k_persist2, dim3(256), dim3(512),
                             kargs, 0, stream);
}

// Round 6
// 604.185 us; speedup vs baseline: 2.1109x; 2.1109x over previous
//
#include <hip/hip_runtime.h>
#include <hip/hip_bf16.h>

typedef __attribute__((ext_vector_type(8))) short short8;
typedef __attribute__((ext_vector_type(4))) float f32x4;
typedef unsigned short u16;

// Problem constants
#define BB 512     // batch
#define HH 1024    // hidden
#define TT 25      // decoder steps
#define CTB 128    // ct slices (each owns 8 hidden cols -> 48 Wc rows)
#define HSZ (BB*HH)   // elements in one h_bf buffer

__device__ __forceinline__ float sigm(float x){ return 1.f/(1.f+__expf(-x)); }
__device__ __forceinline__ float tanh_(float x){
  float e = __expf(-2.f*fabsf(x));
  float t = (1.f-e)/(1.f+e);
  return copysignf(t, x);
}
__device__ __forceinline__ u16 f2bf(float x){
  union { float f; unsigned u; } v; v.f = x;
  unsigned r = v.u + 0x7FFFu + ((v.u>>16)&1u);
  return (u16)(r>>16);
}

#if __has_builtin(__builtin_amdgcn_global_load_lds)
#define GLOAD_LDS16(g, l) __builtin_amdgcn_global_load_lds( \
    (const __attribute__((address_space(1))) void*)(g), \
    (__attribute__((address_space(3))) void*)(l), 16, 0, 0)
#define HAVE_GLL 1
#else
#define HAVE_GLL 0
#endif

// Wcp layout: per ct slice (8 hidden cols), 48 rows (r = gate*8 + u, gates:
// 0=gir 1=giz 2=gin 3=ghr 4=ghz 5=ghn), pre-packed in MFMA B-frag order:
// elem idx = ct*49152 + ((kit*3 + nf)*64 + lane)*8 + e
__device__ __forceinline__ size_t wc_idx(int ct, int r, int k){
  int nf = r>>4, rl = r&15, kit = k>>5, k31 = k&31;
  int lane = rl | (((k31>>3)&3)<<4);
  return (size_t)ct*49152 + ((size_t)(kit*3+nf)*64 + (size_t)lane)*8 + (k31&7);
}

// ---- prep 1: Whh -> Wcp gate rows 3..5 (+cbias), Wout -> WoT (bf16 [96][1024])
__global__ void k_prep_cast(const float* __restrict__ Whh, const float* __restrict__ bhh,
                            const float* __restrict__ Wout,
                            u16* __restrict__ Wcp, float* __restrict__ cbias,
                            u16* __restrict__ WoT){
  int bid = blockIdx.x, tid = threadIdx.x;
  if (bid < 3072){
    int g1 = bid >> 10, j = bid & 1023;
    int ct = j >> 3, u = j & 7, r = (3+g1)*8 + u;
    const float* src = Whh + (size_t)bid*1024;
    if (tid < 128){
      int k0 = tid*8;
      size_t base = wc_idx(ct, r, k0);
      #pragma unroll
      for (int i=0;i<8;i++) Wcp[base+i] = f2bf(src[k0+i]);
    }
    if (!tid) cbias[ct*48 + r] = bhh[bid];
  } else {
    int d = bid - 3072;
    for (int k = tid; k < 1024; k += 256)
      WoT[(size_t)d*1024 + k] = f2bf(Wout[(size_t)k*96 + d]);
  }
}

// ---- prep 2: Wx[n][k] = sum_d Wih[n][d]*Wout[k][d]  (out-proj folded into gi path)
__global__ void k_prep_wx(const float* __restrict__ Wih, const float* __restrict__ Wout,
                          u16* __restrict__ Wcp){
  __shared__ float sWih[32][97];
  __shared__ float sWo[64][97];
  int tid = threadIdx.x;
  int nt = blockIdx.x % 96, kt = blockIdx.x / 96;   // n-tile 32, k-tile 64
  for (int i = tid; i < 32*96; i += 256){ int r2=i/96, d=i%96; sWih[r2][d] = Wih[(size_t)(nt*32+r2)*96 + d]; }
  for (int i = tid; i < 64*96; i += 256){ int r2=i/96, d=i%96; sWo[r2][d]  = Wout[(size_t)(kt*64+r2)*96 + d]; }
  __syncthreads();
  int ni = tid & 31, kb = tid >> 5;    // thread owns 8 consecutive k
  float acc[8];
  #pragma unroll
  for (int i=0;i<8;i++) acc[i]=0.f;
  for (int d = 0; d < 96; d++){
    float a = sWih[ni][d];
    #pragma unroll
    for (int i=0;i<8;i++) acc[i] += a * sWo[kb*8 + i][d];
  }
  int n = nt*32 + ni;
  int g = n >> 10, j = n & 1023;
  int ct = j >> 3, u = j & 7, r = g*8 + u;
  size_t base = wc_idx(ct, r, kt*64 + kb*8);
  #pragma unroll
  for (int i=0;i<8;i++) Wcp[base+i] = f2bf(acc[i]);
}

// ---- prep 3: cbias gi rows: bih[n] + sum_d bout[d]*Wih[n][d]
__global__ void k_prep_cx(const float* __restrict__ Wih, const float* __restrict__ bih,
                          const float* __restrict__ bout, float* __restrict__ cbias){
  int n = blockIdx.x*256 + threadIdx.x;
  if (n >= 3072) return;
  float acc = bih[n];
  const float* wrow = Wih + (size_t)n*96;
  for (int d = 0; d < 96; d++) acc += bout[d]*wrow[d];
  int g = n >> 10, j = n & 1023;
  cbias[(j>>3)*48 + g*8 + (j&7)] = acc;
}

// ---- step 0: h1 = gru(p, 0) in fp32 (gh = bhh exactly since h=0)
// h_f32 COL-MAJOR [1024][512]; h_bf (= hbuf[0]) row-major. Block 0 resets flags.
__global__ void k_step0(const float* __restrict__ dec_in, const float* __restrict__ Wih,
                        const float* __restrict__ bih, const float* __restrict__ bhh,
                        float* __restrict__ h_f32, u16* __restrict__ h_bf,
                        unsigned* __restrict__ flags){
  if (blockIdx.x == 0 && threadIdx.x < 256) flags[threadIdx.x] = 0u;
  __shared__ float sP[64][97];
  __shared__ float sW[64][97];
  int tid = threadIdx.x;
  int bt = blockIdx.x & 7;
  int jt = blockIdx.x >> 3;
  for (int i = tid; i < 64*96; i += 256){ int r=i/96, d=i%96; sP[r][d] = dec_in[(size_t)(bt*64+r)*96 + d]; }
  int tb = tid >> 4, tj = tid & 15;
  float gg[3][4][4];
  for (int g = 0; g < 3; g++){
    __syncthreads();
    for (int i = tid; i < 64*96; i += 256){ int r=i/96, d=i%96; sW[r][d] = Wih[((size_t)g*1024 + jt*64 + r)*96 + d]; }
    __syncthreads();
    float acc[4][4];
    #pragma unroll
    for (int x=0;x<4;x++)
      #pragma unroll
      for (int y=0;y<4;y++) acc[x][y]=0.f;
    for (int d = 0; d < 96; d++){
      float a[4], wv[4];
      #pragma unroll
      for (int x=0;x<4;x++) a[x]  = sP[tb + x*16][d];
      #pragma unroll
      for (int y=0;y<4;y++) wv[y] = sW[tj + y*16][d];
      #pragma unroll
      for (int x=0;x<4;x++)
        #pragma unroll
        for (int y=0;y<4;y++) acc[x][y] += a[x]*wv[y];
    }
    #pragma unroll
    for (int x=0;x<4;x++)
      #pragma unroll
      for (int y=0;y<4;y++) gg[g][x][y] = acc[x][y];
  }
  #pragma unroll
  for (int x=0;x<4;x++)
    #pragma unroll
    for (int y=0;y<4;y++){
      int b = bt*64 + tb + x*16;
      int j = jt*64 + tj + y*16;
      float gir = gg[0][x][y] + bih[j];
      float giz = gg[1][x][y] + bih[1024+j];
      float gin = gg[2][x][y] + bih[2048+j];
      float r = sigm(gir + bhh[j]);
      float z = sigm(giz + bhh[1024+j]);
      float nn = tanh_(gin + r*bhh[2048+j]);
      float h = (1.f - z)*nn;
      h_f32[(size_t)j*512 + b] = h;
      h_bf [(size_t)b*1024 + j] = f2bf(h);
    }
}

// ---- fused out-projection tile: pred[outIdx] rows [bt*256+bm*16,+16) cols [bn*16,+16)
__device__ __forceinline__ void pred_tile(const u16* __restrict__ hin_bf,
    const u16* __restrict__ WoT, const float* __restrict__ bout,
    float* __restrict__ pred, int bt, int ct, int l16, int lk, int outIdx){
  int bm = ct/6, bn = ct%6;
  const short8* Aq = (const short8*)hin_bf + (size_t)(bt*256 + bm*16 + l16)*128 + lk;
  const short8* Bq = (const short8*)WoT   + (size_t)(bn*16 + l16)*128 + lk;
  short8 qa[4], qb[4];
  #pragma unroll
  for (int d=0; d<4; d++){ qa[d]=Aq[d*4]; qb[d]=Bq[d*4]; }
  f32x4 accp = {0.f,0.f,0.f,0.f};
  #pragma unroll
  for (int kit=0; kit<32; kit++){
    int slot = kit & 3;
    short8 a = qa[slot], b = qb[slot];
    if (kit < 28){ qa[slot]=Aq[(kit+4)*4]; qb[slot]=Bq[(kit+4)*4]; }
    accp = __builtin_amdgcn_mfma_f32_16x16x32_bf16(a, b, accp, 0,0,0);
  }
  int c = bn*16 + l16;
  float bb = bout[c];
  #pragma unroll
  for (int j=0;j<4;j++){
    int row = bt*256 + bm*16 + lk*4 + j;
    pred[(size_t)row*2400 + (size_t)outIdx*96 + c] = accp[j] + bb;
  }
}

// ---- persistent kernel, FENCE-FREE sync:
//  * 25 write-once h buffers  -> no stale L2 lines -> no invalidate ever
//  * h stored write-through (system-scope relaxed u32 stores) -> no writeback
//  * per-block flag (monotonic step) released after __syncthreads (vmcnt drained)
//  * f32 carry lives in registers (block identity persistent)
__global__ __launch_bounds__(512)
void k_persist3(const float* __restrict__ hf0, u16* __restrict__ hbase,
                const u16* __restrict__ Wcp, const float* __restrict__ cbias,
                const u16* __restrict__ WoT, const float* __restrict__ bout,
                float* __restrict__ pred, unsigned* __restrict__ flags){
  __shared__ short8 sB[6144];       // 96 KB: Wc slice, staged ONCE
  int b = blockIdx.x, tid = threadIdx.x;
  int lane = tid & 63, w = tid >> 6;          // 8 waves
  int l16 = lane & 15, lk = lane >> 4;
  int r8 = b & 7;
  int bt = r8 >> 2;                           // batch half
  int ct = (b >> 3)*4 + (r8 & 3);             // slice [0,128)

  const short8* Wblk = (const short8*)Wcp + (size_t)ct*6144;
#if HAVE_GLL
  #pragma unroll
  for (int it = 0; it < 12; it++){
    int i = it*512 + tid;
    GLOAD_LDS16(Wblk + i, &sB[i]);
  }
#else
  for (int i = tid; i < 6144; i += 512) sB[i] = Wblk[i];
#endif

  float c0 = cbias[ct*48 +  0 + l16];
  float c1 = cbias[ct*48 + 16 + l16];
  float c2 = cbias[ct*48 + 32 + l16];
  bool hiB = (l16 & 8) != 0;
  bool stLane = !hiB && ((l16 & 1) == 0);     // stores packed col pair (colg, colg+1)
  int colg = ct*8 + (l16 & 7);
  int rowA = bt*256 + w*32;                   // wave owns 32 batch rows
  bool doPred = (ct < 96) && (w == 7);

  // f32 carry in registers (this block's own 8 cols x its rows)
  float hold[2][4];
  if (!hiB){
    #pragma unroll
    for (int mf = 0; mf < 2; mf++){
      f32x4 h4 = *(const f32x4*)(hf0 + (size_t)colg*512 + rowA + mf*16 + lk*4);
      hold[mf][0]=h4[0]; hold[mf][1]=h4[1]; hold[mf][2]=h4[2]; hold[mf][3]=h4[3];
    }
  }
  __syncthreads();   // Wc staging complete

  for (int t = 1; t <= 24; ++t){
    const u16* pin = hbase + (size_t)(t-1)*HSZ;
    u16* pout = hbase + (size_t)t*HSZ;

    // ---- A-prefetch ring (depth 8)
    const short8* Ap = (const short8*)pin + (size_t)(rowA + l16)*128 + lk;
    short8 r0_[8], r1_[8];
    #pragma unroll
    for (int d = 0; d < 8; d++){ r0_[d] = Ap[d*4]; r1_[d] = Ap[d*4 + 2048]; }

    // ---- recurrence: C = h_t[half] @ WcSlice^T
    f32x4 acc[2][3];
    #pragma unroll
    for (int m=0;m<2;m++)
      #pragma unroll
      for (int nf=0;nf<3;nf++) acc[m][nf] = f32x4{0.f,0.f,0.f,0.f};
    #pragma unroll
    for (int kit = 0; kit < 32; kit++){
      const int slot = kit & 7;
      short8 a0 = r0_[slot], a1 = r1_[slot];
      if (kit < 24){ r0_[slot] = Ap[(kit+8)*4]; r1_[slot] = Ap[(kit+8)*4 + 2048]; }
      const short8* Bs = &sB[kit*192 + lane];
      short8 b0 = Bs[0], b1 = Bs[64], b2 = Bs[128];
      acc[0][0] = __builtin_amdgcn_mfma_f32_16x16x32_bf16(a0, b0, acc[0][0], 0,0,0);
      acc[1][0] = __builtin_amdgcn_mfma_f32_16x16x32_bf16(a1, b0, acc[1][0], 0,0,0);
      acc[0][1] = __builtin_amdgcn_mfma_f32_16x16x32_bf16(a0, b1, acc[0][1], 0,0,0);
      acc[1][1] = __builtin_amdgcn_mfma_f32_16x16x32_bf16(a1, b1, acc[1][1], 0,0,0);
      acc[0][2] = __builtin_amdgcn_mfma_f32_16x16x32_bf16(a0, b2, acc[0][2], 0,0,0);
      acc[1][2] = __builtin_amdgcn_mfma_f32_16x16x32_bf16(a1, b2, acc[1][2], 0,0,0);
    }

    // ---- gates via lane pair (l, l^8); lo: gir,gin,ghz  hi: giz,ghr,ghn
    #pragma unroll
    for (int mf=0; mf<2; mf++){
      #pragma unroll
      for (int j=0;j<4;j++){
        int batch = rowA + mf*16 + lk*4 + j;
        float g0 = acc[mf][0][j] + c0;
        float g1 = acc[mf][1][j] + c1;
        float g2 = acc[mf][2][j] + c2;
        float v1 = hiB ? g1 : g2;
        float w1 = __shfl_xor(v1, 8, 64);
        float rz = sigm(g0 + w1);
        float w2 = __shfl_xor(rz, 8, 64);
        float v3 = hiB ? (w2 * g2) : 0.f;
        float w3 = __shfl_xor(v3, 8, 64);
        float hnew = 0.f;
        if (!hiB){
          float nn = tanh_(g1 + w3);
          hnew = (1.f - w2)*nn + w2*hold[mf][j];
          hold[mf][j] = hnew;
        }
        float other = __shfl_xor(hnew, 1, 64);   // partner col's hnew
        if (stLane){
          unsigned pk = ((unsigned)f2bf(other) << 16) | (unsigned)f2bf(hnew);
          __hip_atomic_store((unsigned*)(pout + (size_t)batch*1024 + colg), pk,
                             __ATOMIC_RELAXED, __HIP_MEMORY_SCOPE_SYSTEM);
        }
      }
    }

    // ---- fence-free barrier
    __syncthreads();   // drains every wave's stores (vmcnt 0 before s_barrier)
    if (tid == 0)
      __hip_atomic_store(&flags[b], (unsigned)t,
                         __ATOMIC_RELAXED, __HIP_MEMORY_SCOPE_SYSTEM);
    if (doPred) pred_tile(pin, WoT, bout, pred, bt, ct, l16, lk, t-1);
    if (tid < 128){
      unsigned tgt = (unsigned)t;
      while (__hip_atomic_load(&flags[tid], __ATOMIC_RELAXED,
                               __HIP_MEMORY_SCOPE_SYSTEM) < tgt ||
             __hip_atomic_load(&flags[tid+128], __ATOMIC_RELAXED,
                               __HIP_MEMORY_SCOPE_SYSTEM) < tgt)
        __builtin_amdgcn_s_sleep(2);
    }
    __syncthreads();
  }
  // final pred index 24 from h_25 = hbuf[24]
  if (doPred) pred_tile(hbase + (size_t)24*HSZ, WoT, bout, pred, bt, ct, l16, lk, 24);
}

extern "C" void kernel_launch(void* const* d_in, const int* in_sizes, int n_in,
                              void* d_out, int out_size, void* d_ws, size_t ws_size,
                              hipStream_t stream){
  // inputs: 0 enc_in, 1 dec_in, 2..5 enc_* (DEAD CODE), 6 dec_Wih, 7 dec_Whh,
  //         8 dec_bih, 9 dec_bhh, 10 W_out, 11 b_out
  const float* dec_in = (const float*)d_in[1];
  const float* Wih  = (const float*)d_in[6];
  const float* Whh  = (const float*)d_in[7];
  const float* bih  = (const float*)d_in[8];
  const float* bhh  = (const float*)d_in[9];
  const float* Wout = (const float*)d_in[10];
  const float* bout = (const float*)d_in[11];
  float* pred = (float*)d_out;   // [512][25][96] fp32

  char* ws = (char*)d_ws;
  size_t off = 0;
  u16* Wcp = (u16*)(ws + off);   off += (size_t)CTB*48*1024*2;     // 12.58 MB
  u16* WoT = (u16*)(ws + off);   off += (size_t)96*1024*2;
  float* cbias = (float*)(ws + off); off += (size_t)6144*4;
  off = (off + 255) & ~(size_t)255;
  float* hf0 = (float*)(ws + off); off += (size_t)BB*HH*4;   // col-major f32 carry seed
  u16* hbase = (u16*)(ws + off);   off += (size_t)TT*HSZ*2;  // 25 write-once bf16 buffers
  off = (off + 255) & ~(size_t)255;
  unsigned* flags = (unsigned*)(ws + off); off += 1024;

  k_prep_cast<<<3168, 256, 0, stream>>>(Whh, bhh, Wout, Wcp, cbias, WoT);
  k_prep_wx  <<<1536, 256, 0, stream>>>(Wih, Wout, Wcp);
  k_prep_cx  <<<12,   256, 0, stream>>>(Wih, bih, bout, cbias);
  k_step0    <<<128,  256, 0, stream>>>(dec_in, Wih, bih, bhh, hf0, hbase, flags);

  const float* hf0_c = hf0;
  void* kargs[] = {(void*)&hf0_c, (void*)&hbase, (void*)&Wcp, (void*)&cbias,
                   (void*)&WoT, (void*)&bout, (void*)&pred, (void*)&flags};
  hipLaunchCooperativeKernel((const void*)k_persist3, dim3(256), dim3(512),
                             kargs, 0, stream);
}

// Round 7
// 596.382 us; speedup vs baseline: 2.1385x; 1.0131x over previous
//
#include <hip/hip_runtime.h>
#include <hip/hip_bf16.h>

typedef __attribute__((ext_vector_type(8))) short short8;
typedef __attribute__((ext_vector_type(4))) float f32x4;
typedef __attribute__((ext_vector_type(4))) unsigned u32x4;
typedef unsigned short u16;

// Problem constants
#define BB 512     // batch
#define HH 1024    // hidden
#define TT 25      // decoder steps
#define CTB 128    // ct slices (each owns 8 hidden cols -> 48 Wc rows)
#define HSZ (BB*HH)   // elements in one h_bf buffer

__device__ __forceinline__ float sigm(float x){ return 1.f/(1.f+__expf(-x)); }
__device__ __forceinline__ float tanh_(float x){
  float e = __expf(-2.f*fabsf(x));
  float t = (1.f-e)/(1.f+e);
  return copysignf(t, x);
}
__device__ __forceinline__ u16 f2bf(float x){
  union { float f; unsigned u; } v; v.f = x;
  unsigned r = v.u + 0x7FFFu + ((v.u>>16)&1u);
  return (u16)(r>>16);
}
// 16B write-through store (visible at coherence point after vmcnt drain)
__device__ __forceinline__ void store16_wt(void* p, u32x4 v){
  asm volatile("global_store_dwordx4 %0, %1, off sc0 sc1" :: "v"(p), "v"(v) : "memory");
}

#if __has_builtin(__builtin_amdgcn_global_load_lds)
#define GLOAD_LDS16(g, l) __builtin_amdgcn_global_load_lds( \
    (const __attribute__((address_space(1))) void*)(g), \
    (__attribute__((address_space(3))) void*)(l), 16, 0, 0)
#define HAVE_GLL 1
#else
#define HAVE_GLL 0
#endif

// Wcp layout: per ct slice (8 hidden cols), 48 rows (r = gate*8 + u, gates:
// 0=gir 1=giz 2=gin 3=ghr 4=ghz 5=ghn), pre-packed in MFMA B-frag order:
// elem idx = ct*49152 + ((kit*3 + nf)*64 + lane)*8 + e
__device__ __forceinline__ size_t wc_idx(int ct, int r, int k){
  int nf = r>>4, rl = r&15, kit = k>>5, k31 = k&31;
  int lane = rl | (((k31>>3)&3)<<4);
  return (size_t)ct*49152 + ((size_t)(kit*3+nf)*64 + (size_t)lane)*8 + (k31&7);
}

// ---- prep 1: Whh -> Wcp gate rows 3..5 (+cbias), Wout -> WoT (bf16 [96][1024])
__global__ void k_prep_cast(const float* __restrict__ Whh, const float* __restrict__ bhh,
                            const float* __restrict__ Wout,
                            u16* __restrict__ Wcp, float* __restrict__ cbias,
                            u16* __restrict__ WoT){
  int bid = blockIdx.x, tid = threadIdx.x;
  if (bid < 3072){
    int g1 = bid >> 10, j = bid & 1023;
    int ct = j >> 3, u = j & 7, r = (3+g1)*8 + u;
    const float* src = Whh + (size_t)bid*1024;
    if (tid < 128){
      int k0 = tid*8;
      size_t base = wc_idx(ct, r, k0);
      #pragma unroll
      for (int i=0;i<8;i++) Wcp[base+i] = f2bf(src[k0+i]);
    }
    if (!tid) cbias[ct*48 + r] = bhh[bid];
  } else {
    int d = bid - 3072;
    for (int k = tid; k < 1024; k += 256)
      WoT[(size_t)d*1024 + k] = f2bf(Wout[(size_t)k*96 + d]);
  }
}

// ---- prep 2: Wx[n][k] = sum_d Wih[n][d]*Wout[k][d]  (out-proj folded into gi path)
__global__ void k_prep_wx(const float* __restrict__ Wih, const float* __restrict__ Wout,
                          u16* __restrict__ Wcp){
  __shared__ float sWih[32][97];
  __shared__ float sWo[64][97];
  int tid = threadIdx.x;
  int nt = blockIdx.x % 96, kt = blockIdx.x / 96;   // n-tile 32, k-tile 64
  for (int i = tid; i < 32*96; i += 256){ int r2=i/96, d=i%96; sWih[r2][d] = Wih[(size_t)(nt*32+r2)*96 + d]; }
  for (int i = tid; i < 64*96; i += 256){ int r2=i/96, d=i%96; sWo[r2][d]  = Wout[(size_t)(kt*64+r2)*96 + d]; }
  __syncthreads();
  int ni = tid & 31, kb = tid >> 5;    // thread owns 8 consecutive k
  float acc[8];
  #pragma unroll
  for (int i=0;i<8;i++) acc[i]=0.f;
  for (int d = 0; d < 96; d++){
    float a = sWih[ni][d];
    #pragma unroll
    for (int i=0;i<8;i++) acc[i] += a * sWo[kb*8 + i][d];
  }
  int n = nt*32 + ni;
  int g = n >> 10, j = n & 1023;
  int ct = j >> 3, u = j & 7, r = g*8 + u;
  size_t base = wc_idx(ct, r, kt*64 + kb*8);
  #pragma unroll
  for (int i=0;i<8;i++) Wcp[base+i] = f2bf(acc[i]);
}

// ---- prep 3: cbias gi rows: bih[n] + sum_d bout[d]*Wih[n][d]
__global__ void k_prep_cx(const float* __restrict__ Wih, const float* __restrict__ bih,
                          const float* __restrict__ bout, float* __restrict__ cbias){
  int n = blockIdx.x*256 + threadIdx.x;
  if (n >= 3072) return;
  float acc = bih[n];
  const float* wrow = Wih + (size_t)n*96;
  for (int d = 0; d < 96; d++) acc += bout[d]*wrow[d];
  int g = n >> 10, j = n & 1023;
  cbias[(j>>3)*48 + g*8 + (j&7)] = acc;
}

// ---- step 0: h1 = gru(p, 0) in fp32 (gh = bhh exactly since h=0)
// h_f32 COL-MAJOR [1024][512]; h_bf (= hbuf[0]) row-major. Block 0 resets flags.
__global__ void k_step0(const float* __restrict__ dec_in, const float* __restrict__ Wih,
                        const float* __restrict__ bih, const float* __restrict__ bhh,
                        float* __restrict__ h_f32, u16* __restrict__ h_bf,
                        unsigned* __restrict__ flags){
  if (blockIdx.x == 0 && threadIdx.x < 256) flags[threadIdx.x] = 0u;
  __shared__ float sP[64][97];
  __shared__ float sW[64][97];
  int tid = threadIdx.x;
  int bt = blockIdx.x & 7;
  int jt = blockIdx.x >> 3;
  for (int i = tid; i < 64*96; i += 256){ int r=i/96, d=i%96; sP[r][d] = dec_in[(size_t)(bt*64+r)*96 + d]; }
  int tb = tid >> 4, tj = tid & 15;
  float gg[3][4][4];
  for (int g = 0; g < 3; g++){
    __syncthreads();
    for (int i = tid; i < 64*96; i += 256){ int r=i/96, d=i%96; sW[r][d] = Wih[((size_t)g*1024 + jt*64 + r)*96 + d]; }
    __syncthreads();
    float acc[4][4];
    #pragma unroll
    for (int x=0;x<4;x++)
      #pragma unroll
      for (int y=0;y<4;y++) acc[x][y]=0.f;
    for (int d = 0; d < 96; d++){
      float a[4], wv[4];
      #pragma unroll
      for (int x=0;x<4;x++) a[x]  = sP[tb + x*16][d];
      #pragma unroll
      for (int y=0;y<4;y++) wv[y] = sW[tj + y*16][d];
      #pragma unroll
      for (int x=0;x<4;x++)
        #pragma unroll
        for (int y=0;y<4;y++) acc[x][y] += a[x]*wv[y];
    }
    #pragma unroll
    for (int x=0;x<4;x++)
      #pragma unroll
      for (int y=0;y<4;y++) gg[g][x][y] = acc[x][y];
  }
  #pragma unroll
  for (int x=0;x<4;x++)
    #pragma unroll
    for (int y=0;y<4;y++){
      int b = bt*64 + tb + x*16;
      int j = jt*64 + tj + y*16;
      float gir = gg[0][x][y] + bih[j];
      float giz = gg[1][x][y] + bih[1024+j];
      float gin = gg[2][x][y] + bih[2048+j];
      float r = sigm(gir + bhh[j]);
      float z = sigm(giz + bhh[1024+j]);
      float nn = tanh_(gin + r*bhh[2048+j]);
      float h = (1.f - z)*nn;
      h_f32[(size_t)j*512 + b] = h;
      h_bf [(size_t)b*1024 + j] = f2bf(h);
    }
}

// ---- persistent kernel, fence-free sync (write-once h buffers + write-through
// stores + per-half flag barrier). pred split-K across all 8 waves.
__global__ __launch_bounds__(512)
void k_persist4(const float* __restrict__ hf0, u16* __restrict__ hbase,
                const u16* __restrict__ Wcp, const float* __restrict__ cbias,
                const u16* __restrict__ WoT, const float* __restrict__ bout,
                float* __restrict__ pred, unsigned* __restrict__ flags){
  __shared__ short8 sB[6144];       // 96 KB: Wc slice, staged ONCE
  __shared__ f32x4 sPred[8][64];    // 8 KB: pred split-K partials
  int b = blockIdx.x, tid = threadIdx.x;
  int lane = tid & 63, w = tid >> 6;          // 8 waves
  int l16 = lane & 15, lk = lane >> 4;
  int r8 = b & 7;
  int bt = r8 >> 2;                           // batch half (XCDs 0-3 / 4-7)
  int ct = (b >> 3)*4 + (r8 & 3);             // slice [0,128)

  const short8* Wblk = (const short8*)Wcp + (size_t)ct*6144;
#if HAVE_GLL
  #pragma unroll
  for (int it = 0; it < 12; it++){
    int i = it*512 + tid;
    GLOAD_LDS16(Wblk + i, &sB[i]);
  }
#else
  for (int i = tid; i < 6144; i += 512) sB[i] = Wblk[i];
#endif

  float c0 = cbias[ct*48 +  0 + l16];
  float c1 = cbias[ct*48 + 16 + l16];
  float c2 = cbias[ct*48 + 32 + l16];
  bool hiB = (l16 & 8) != 0;
  int rowA = bt*256 + w*32;                   // wave owns 32 batch rows
  bool doPredBlk = (ct < 96);
  int bm = ct/6, bn = ct%6;
  int myFlag = bt*128 + ct;

  // f32 carry in registers (this block's own 8 cols x its rows)
  float hold[2][4];
  if (!hiB){
    int colg = ct*8 + (l16 & 7);
    #pragma unroll
    for (int mf = 0; mf < 2; mf++){
      f32x4 h4 = *(const f32x4*)(hf0 + (size_t)colg*512 + rowA + mf*16 + lk*4);
      hold[mf][0]=h4[0]; hold[mf][1]=h4[1]; hold[mf][2]=h4[2]; hold[mf][3]=h4[3];
    }
  }
  __syncthreads();   // Wc staging complete

  for (int t = 1; t <= 24; ++t){
    const u16* pin = hbase + (size_t)(t-1)*HSZ;
    u16* pout = hbase + (size_t)t*HSZ;

    // ---- A-prefetch ring (depth 12)
    const short8* Ap = (const short8*)pin + (size_t)(rowA + l16)*128 + lk;
    short8 r0_[12], r1_[12];
    #pragma unroll
    for (int d = 0; d < 12; d++){ r0_[d] = Ap[d*4]; r1_[d] = Ap[d*4 + 2048]; }

    // ---- recurrence: C = h_t[half] @ WcSlice^T
    f32x4 acc[2][3];
    #pragma unroll
    for (int m=0;m<2;m++)
      #pragma unroll
      for (int nf=0;nf<3;nf++) acc[m][nf] = f32x4{0.f,0.f,0.f,0.f};
    #pragma unroll
    for (int kit = 0; kit < 32; kit++){
      const int slot = kit % 12;
      short8 a0 = r0_[slot], a1 = r1_[slot];
      if (kit < 20){ r0_[slot] = Ap[(kit+12)*4]; r1_[slot] = Ap[(kit+12)*4 + 2048]; }
      const short8* Bs = &sB[kit*192 + lane];
      short8 b0 = Bs[0], b1 = Bs[64], b2 = Bs[128];
      acc[0][0] = __builtin_amdgcn_mfma_f32_16x16x32_bf16(a0, b0, acc[0][0], 0,0,0);
      acc[1][0] = __builtin_amdgcn_mfma_f32_16x16x32_bf16(a1, b0, acc[1][0], 0,0,0);
      acc[0][1] = __builtin_amdgcn_mfma_f32_16x16x32_bf16(a0, b1, acc[0][1], 0,0,0);
      acc[1][1] = __builtin_amdgcn_mfma_f32_16x16x32_bf16(a1, b1, acc[1][1], 0,0,0);
      acc[0][2] = __builtin_amdgcn_mfma_f32_16x16x32_bf16(a0, b2, acc[0][2], 0,0,0);
      acc[1][2] = __builtin_amdgcn_mfma_f32_16x16x32_bf16(a1, b2, acc[1][2], 0,0,0);
    }

    // ---- gates via lane pair (l, l^8); lo: gir,gin,ghz  hi: giz,ghr,ghn
    // then in-wave 8x8 transpose -> one 16B write-through store per batch row
    #pragma unroll
    for (int mf=0; mf<2; mf++){
      #pragma unroll
      for (int j=0;j<4;j++){
        int batch = rowA + mf*16 + lk*4 + j;
        float g0 = acc[mf][0][j] + c0;
        float g1 = acc[mf][1][j] + c1;
        float g2 = acc[mf][2][j] + c2;
        float v1 = hiB ? g1 : g2;
        float w1 = __shfl_xor(v1, 8, 64);
        float rz = sigm(g0 + w1);
        float w2 = __shfl_xor(rz, 8, 64);
        float v3 = hiB ? (w2 * g2) : 0.f;
        float w3 = __shfl_xor(v3, 8, 64);
        float hnew = 0.f;
        if (!hiB){
          float nn = tanh_(g1 + w3);
          hnew = (1.f - w2)*nn + w2*hold[mf][j];
          hold[mf][j] = hnew;
        }
        // gather cols 0..7 of this batch into lane l16==0 of each lk group
        float o1 = __shfl_xor(hnew, 1, 64);
        unsigned pk = ((unsigned)f2bf(o1) << 16) | (unsigned)f2bf(hnew); // cols[l16,l16+1] at even l16
        unsigned pk2 = __shfl_xor(pk, 2, 64);       // lane0: cols[2,3]; lane4: cols[6,7]
        unsigned q2 = __shfl_xor(pk, 4, 64);        // lane0: cols[4,5]
        unsigned q3 = __shfl_xor(pk2, 4, 64);       // lane0: cols[6,7]
        if (l16 == 0){
          u32x4 vv = {pk, pk2, q2, q3};
          store16_wt((char*)pout + (size_t)batch*2048 + (size_t)ct*16, vv);
        }
      }
    }

    // ---- barrier: release, pred partials in the slack, reduce+poll, join
    __syncthreads();   // drains every wave's stores (vmcnt 0 before s_barrier)
    if (tid == 0)
      __hip_atomic_store(&flags[myFlag], (unsigned)t,
                         __ATOMIC_RELAXED, __HIP_MEMORY_SCOPE_AGENT);
    if (doPredBlk){    // pred[t-1] = h_t @ Wout + bout, split-K over 8 waves
      const short8* Aq = (const short8*)pin + (size_t)(bt*256 + bm*16 + l16)*128 + lk;
      const short8* Bq = (const short8*)WoT + (size_t)(bn*16 + l16)*128 + lk;
      f32x4 accp = {0.f,0.f,0.f,0.f};
      #pragma unroll
      for (int q = 0; q < 4; q++){
        int kit = w*4 + q;
        accp = __builtin_amdgcn_mfma_f32_16x16x32_bf16(Aq[kit*4], Bq[kit*4], accp, 0,0,0);
      }
      sPred[w][lane] = accp;
    }
    __syncthreads();
    if (doPredBlk && w == 0){
      f32x4 s = sPred[0][lane];
      #pragma unroll
      for (int ww=1; ww<8; ww++) s += sPred[ww][lane];
      int c = bn*16 + l16;
      float bb = bout[c];
      #pragma unroll
      for (int j=0;j<4;j++){
        int row = bt*256 + bm*16 + lk*4 + j;
        pred[(size_t)row*2400 + (size_t)(t-1)*96 + c] = s[j] + bb;
      }
    }
    if (tid >= 64 && tid < 192){
      unsigned tgt = (unsigned)t;
      while (__hip_atomic_load(&flags[bt*128 + (tid-64)], __ATOMIC_RELAXED,
                               __HIP_MEMORY_SCOPE_AGENT) < tgt)
        __builtin_amdgcn_s_sleep(2);
    }
    __syncthreads();
  }

  // final pred index 24 from h_25 = hbuf[24]
  if (doPredBlk){
    const u16* pin = hbase + (size_t)24*HSZ;
    const short8* Aq = (const short8*)pin + (size_t)(bt*256 + bm*16 + l16)*128 + lk;
    const short8* Bq = (const short8*)WoT + (size_t)(bn*16 + l16)*128 + lk;
    f32x4 accp = {0.f,0.f,0.f,0.f};
    #pragma unroll
    for (int q = 0; q < 4; q++){
      int kit = w*4 + q;
      accp = __builtin_amdgcn_mfma_f32_16x16x32_bf16(Aq[kit*4], Bq[kit*4], accp, 0,0,0);
    }
    sPred[w][lane] = accp;
    __syncthreads();
    if (w == 0){
      f32x4 s = sPred[0][lane];
      #pragma unroll
      for (int ww=1; ww<8; ww++) s += sPred[ww][lane];
      int c = bn*16 + l16;
      float bb = bout[c];
      #pragma unroll
      for (int j=0;j<4;j++){
        int row = bt*256 + bm*16 + lk*4 + j;
        pred[(size_t)row*2400 + (size_t)24*96 + c] = s[j] + bb;
      }
    }
  }
}

extern "C" void kernel_launch(void* const* d_in, const int* in_sizes, int n_in,
                              void* d_out, int out_size, void* d_ws, size_t ws_size,
                              hipStream_t stream){
  // inputs: 0 enc_in, 1 dec_in, 2..5 enc_* (DEAD CODE), 6 dec_Wih, 7 dec_Whh,
  //         8 dec_bih, 9 dec_bhh, 10 W_out, 11 b_out
  const float* dec_in = (const float*)d_in[1];
  const float* Wih  = (const float*)d_in[6];
  const float* Whh  = (const float*)d_in[7];
  const float* bih  = (const float*)d_in[8];
  const float* bhh  = (const float*)d_in[9];
  const float* Wout = (const float*)d_in[10];
  const float* bout = (const float*)d_in[11];
  float* pred = (float*)d_out;   // [512][25][96] fp32

  char* ws = (char*)d_ws;
  size_t off = 0;
  u16* Wcp = (u16*)(ws + off);   off += (size_t)CTB*48*1024*2;     // 12.58 MB
  u16* WoT = (u16*)(ws + off);   off += (size_t)96*1024*2;
  float* cbias = (float*)(ws + off); off += (size_t)6144*4;
  off = (off + 255) & ~(size_t)255;
  float* hf0 = (float*)(ws + off); off += (size_t)BB*HH*4;   // col-major f32 carry seed
  u16* hbase = (u16*)(ws + off);   off += (size_t)TT*HSZ*2;  // 25 write-once bf16 buffers
  off = (off + 255) & ~(size_t)255;
  unsigned* flags = (unsigned*)(ws + off); off += 1024;

  k_prep_cast<<<3168, 256, 0, stream>>>(Whh, bhh, Wout, Wcp, cbias, WoT);
  k_prep_wx  <<<1536, 256, 0, stream>>>(Wih, Wout, Wcp);
  k_prep_cx  <<<12,   256, 0, stream>>>(Wih, bih, bout, cbias);
  k_step0    <<<128,  256, 0, stream>>>(dec_in, Wih, bih, bhh, hf0, hbase, flags);

  const float* hf0_c = hf0;
  void* kargs[] = {(void*)&hf0_c, (void*)&hbase, (void*)&Wcp, (void*)&cbias,
                   (void*)&WoT, (void*)&bout, (void*)&pred, (void*)&flags};
  hipLaunchCooperativeKernel((const void*)k_persist4, dim3(256), dim3(512),
                             kargs, 0, stream);
}